// Round 1
// baseline (75.176 us; speedup 1.0000x reference)
//
#include <hip/hip_runtime.h>
#include <math.h>

#define NB 4
#define NCTX 2048
#define NLAT 256
#define NT 34
#define NSUB 16
#define NRK 16
#define NH 768
#define NW 768

// workspace float offsets
#define OFF_XT  0u        // 4*1024
#define OFF_XR  4096u     // 4*256
#define OFF_XI  5120u     // 4*256
#define OFF_TR  6144u     // 4*34*16*16*2 = 69632
#define OFF_BE  75776u    // 4*16*16
#define OFF_GI  76800u    // 4*16*768*2
#define OFF_GJ  175104u   // 4*16*768*2

// K1: xt[b][j] = sum_i x[b][i]*Wc[j][i] + bc[j]
__global__ __launch_bounds__(256) void k1_xt(const float* __restrict__ x,
                                             const float* __restrict__ Wc,
                                             const float* __restrict__ bc,
                                             float* __restrict__ xt) {
  const int j = blockIdx.x;
  const int tid = threadIdx.x;
  const float* wrow = Wc + (size_t)j * NCTX;
  float a0 = 0.f, a1 = 0.f, a2 = 0.f, a3 = 0.f;
  for (int i = tid; i < NCTX; i += 256) {
    float w = wrow[i];
    a0 += x[i] * w;
    a1 += x[NCTX + i] * w;
    a2 += x[2 * NCTX + i] * w;
    a3 += x[3 * NCTX + i] * w;
  }
  __shared__ float red[4][256];
  red[0][tid] = a0; red[1][tid] = a1; red[2][tid] = a2; red[3][tid] = a3;
  __syncthreads();
  const int wv = tid >> 6, lane = tid & 63;
  float s = red[wv][lane] + red[wv][lane + 64] + red[wv][lane + 128] + red[wv][lane + 192];
  #pragma unroll
  for (int off = 32; off > 0; off >>= 1) s += __shfl_down(s, off, 64);
  if (lane == 0) xt[(size_t)wv * 1024 + j] = s + bc[j];
}

// K2: xm = xt[:, :512] * siglog(xt[:, 512:]) -> xr/xi (interleaved pairs)
__global__ void k2_xm(const float* __restrict__ xt, float* __restrict__ xr,
                      float* __restrict__ xi) {
  const int b = blockIdx.x;
  const int i = threadIdx.x;  // 512 threads
  float xa = xt[b * 1024 + i];
  float xb = xt[b * 1024 + 512 + i];
  float sl = copysignf(log1pf(fabsf(xb)), xb);  // sign(0)*log1p(0)=0 either way
  float v = xa * sl;
  if (i & 1) xi[b * 256 + (i >> 1)] = v;
  else       xr[b * 256 + (i >> 1)] = v;
}

// K3: Re/Im einsum over l, then collapse the broadcast mag math -> trans[b][t][c][r][2]
__global__ __launch_bounds__(256) void k3_trans(const float* __restrict__ GR,
                                                const float* __restrict__ GIm,
                                                const float* __restrict__ xr,
                                                const float* __restrict__ xi,
                                                float* __restrict__ tr) {
  const int t = blockIdx.x >> 4;
  const int c = blockIdx.x & 15;
  const int tid = threadIdx.x;
  __shared__ float gr_s[4096];
  __shared__ float gi_s[4096];
  __shared__ float xr_s[4][260];
  __shared__ float xi_s[4][260];
  const float* grp = GR + (size_t)(t * 16 + c) * 4096;
  const float* gip = GIm + (size_t)(t * 16 + c) * 4096;
  for (int k = tid; k < 4096; k += 256) { gr_s[k] = grp[k]; gi_s[k] = gip[k]; }
  for (int k = tid; k < 1024; k += 256) {
    xr_s[k >> 8][k & 255] = xr[k];
    xi_s[k >> 8][k & 255] = xi[k];
  }
  __syncthreads();
  if (tid < 64) {
    const int r = tid & 15, b = tid >> 4;
    float are = 0.f, aim = 0.f;
    for (int l = 0; l < 256; ++l) {
      float gr = gr_s[l * 16 + r], gi = gi_s[l * 16 + r];
      float vr = xr_s[b][l], vi = xi_s[b][l];
      are += vr * gr - vi * gi;
      aim += vr * gi + vi * gr;
    }
    float mag = sqrtf(are * are + aim * aim + 1e-12f);
    float scale = 256.f * mag / (256.f * mag + 1e-12f);
    size_t o = ((((size_t)b * NT + t) * 16 + c) * 16 + r) * 2;
    tr[o]     = are * scale;
    tr[o + 1] = aim * scale;
  }
}

// K4: tRe/tIm = x @ w_mix, beta = softmax over r of |t|
__global__ __launch_bounds__(64) void k4_beta(const float* __restrict__ wm,
                                              const float* __restrict__ xr,
                                              const float* __restrict__ xi,
                                              float* __restrict__ beta) {
  const int kq = blockIdx.x;     // k quarter
  const int b = blockIdx.y;
  const int lane = threadIdx.x;  // 64
  const int k = kq * 64 + lane;
  __shared__ float xr_s[256], xi_s[256];
  for (int l = lane; l < 256; l += 64) { xr_s[l] = xr[b * 256 + l]; xi_s[l] = xi[b * 256 + l]; }
  __syncthreads();
  const float2* wm2 = (const float2*)wm;
  float tre = 0.f, tim = 0.f;
  for (int l = 0; l < 256; ++l) {
    float2 w = wm2[l * 256 + k];
    float vr = xr_s[l], vi = xi_s[l];
    tre += vr * w.x - vi * w.y;
    tim += vr * w.y + vi * w.x;
  }
  float val = sqrtf(tre * tre + tim * tim + 1e-12f);
  float m = val;
  #pragma unroll
  for (int off = 8; off > 0; off >>= 1) m = fmaxf(m, __shfl_xor(m, off, 16));
  float e = expf(val - m);
  float ssum = e;
  #pragma unroll
  for (int off = 8; off > 0; off >>= 1) ssum += __shfl_xor(ssum, off, 16);
  beta[b * 256 + k] = e / ssum;
}

// K5: build si/sj (space + shift, lerp'd z, cmul), apply inv (cmul for I, cdiv for J),
// beta-weighted sum over r. which = blockIdx.z: 0 -> gI (H), 1 -> gJ (W).
__global__ __launch_bounds__(256) void k5_g(const float* __restrict__ space_i,
                                            const float* __restrict__ space_j,
                                            const float* __restrict__ invs,
                                            const float* __restrict__ tr,
                                            const float* __restrict__ beta,
                                            float* __restrict__ gI,
                                            float* __restrict__ gJ) {
  const int c = blockIdx.x, b = blockIdx.y, which = blockIdx.z;
  const int tid = threadIdx.x;
  __shared__ float sh_shift[16][2];
  __shared__ float sh_z[16][16][2];  // [rt][r][comp]
  __shared__ float sh_beta[16];
  if (tid < 32) {
    int r = tid >> 1, comp = tid & 1;
    sh_shift[r][comp] = tr[((((size_t)b * NT + which) * 16 + c) * 16 + r) * 2 + comp];
  }
  if (tid < 16) sh_beta[tid] = beta[(b * 16 + c) * 16 + tid];
  for (int idx = tid; idx < 512; idx += 256) {
    int rt = idx >> 5, r = (idx >> 1) & 15, comp = idx & 1;
    int t = 2 + which * 16 + rt;
    sh_z[rt][r][comp] = tr[((((size_t)b * NT + t) * 16 + c) * 16 + r) * 2 + comp];
  }
  const float inv_re = invs[c * 2], inv_im = invs[c * 2 + 1];
  __syncthreads();
  const float2* sp2 = (const float2*)(which == 0 ? space_i : space_j);
  sp2 += (size_t)c * 16 * 768;
  float2* gout = (float2*)(which == 0 ? gI : gJ);
  gout += (size_t)(b * 16 + c) * 768;
  for (int h = tid; h < 768; h += 256) {
    float pos = ((float)h + 0.5f) * (16.f / 768.f) - 0.5f;
    pos = fminf(fmaxf(pos, 0.f), 15.f);
    int lo = (int)floorf(pos);
    int hi = min(lo + 1, 15);
    float w = pos - (float)lo;
    float accR = 0.f, accI = 0.f;
    #pragma unroll
    for (int r = 0; r < 16; ++r) {
      float2 sp = sp2[r * 768 + h];
      float spr = sp.x + sh_shift[r][0];
      float spi = sp.y + sh_shift[r][1];
      float ztr = sh_z[lo][r][0] * (1.f - w) + sh_z[hi][r][0] * w;
      float zti = sh_z[lo][r][1] * (1.f - w) + sh_z[hi][r][1] * w;
      float sre = spr * ztr - spi * zti;
      float sim = spr * zti + spi * ztr;
      float br = sh_beta[r];
      if (which == 0) {
        accR += br * sre;
        accI += br * sim;
      } else {
        float den = fmaxf(sre * sre + sim * sim, 1e-4f);
        float id = 1.f / den;
        accR += br * (inv_re * sre + inv_im * sim) * id;
        accI += br * (inv_im * sre - inv_re * sim) * id;
      }
    }
    float2 o;
    if (which == 0) {  // gI = cmul(sum, inv)  (linearity of cmul in first arg)
      o.x = accR * inv_re - accI * inv_im;
      o.y = accR * inv_im + accI * inv_re;
    } else {
      o.x = accR; o.y = accI;
    }
    gout[h] = o;
  }
}

// K6: out[b][h][w] = sum_c ((gIr*gJr - gIi*gJi)*pr + (gIr*gJi + gIi*gJr)*pi) / sqrt(pr^2+pi^2+EPS)
__global__ __launch_bounds__(256) void k6_out(const float* __restrict__ proj,
                                              const float* __restrict__ gI,
                                              const float* __restrict__ gJ,
                                              float* __restrict__ out) {
  const int w0 = blockIdx.x * 16;
  const int h0 = blockIdx.y * 16;
  const int tid = threadIdx.x;
  const int tw = tid & 15, th = tid >> 4;
  __shared__ float2 gIs[64][16];  // [b*16+c][hh]
  __shared__ float2 gJs[64][16];  // [b*16+c][ww]
  const float2* gI2 = (const float2*)gI;
  const float2* gJ2 = (const float2*)gJ;
  for (int idx = tid; idx < 1024; idx += 256) {
    int i = idx & 15, bcp = idx >> 4;
    gIs[bcp][i] = gI2[(size_t)bcp * 768 + h0 + i];
    gJs[bcp][i] = gJ2[(size_t)bcp * 768 + w0 + i];
  }
  __syncthreads();
  const int h = h0 + th, w = w0 + tw;
  const float2* proj2 = (const float2*)proj;
  float acc[4] = {0.f, 0.f, 0.f, 0.f};
  #pragma unroll
  for (int c = 0; c < 16; ++c) {
    float2 p = proj2[((size_t)c * 768 + h) * 768 + w];
    float invden = 1.0f / sqrtf(p.x * p.x + p.y * p.y + 1e-12f);
    float pr = p.x * invden, pi = p.y * invden;
    #pragma unroll
    for (int b = 0; b < 4; ++b) {
      float2 gi = gIs[b * 16 + c][th];
      float2 gj = gJs[b * 16 + c][tw];
      float wRe = gi.x * gj.x - gi.y * gj.y;
      float wIm = gi.x * gj.y + gi.y * gj.x;
      acc[b] += wRe * pr + wIm * pi;
    }
  }
  #pragma unroll
  for (int b = 0; b < 4; ++b)
    out[((size_t)b * 768 + h) * 768 + w] = acc[b];
}

extern "C" void kernel_launch(void* const* d_in, const int* in_sizes, int n_in,
                              void* d_out, int out_size, void* d_ws, size_t ws_size,
                              hipStream_t stream) {
  (void)in_sizes; (void)n_in; (void)out_size; (void)ws_size;
  const float* x    = (const float*)d_in[0];
  const float* Wc   = (const float*)d_in[1];
  const float* bc   = (const float*)d_in[2];
  const float* spi  = (const float*)d_in[3];
  const float* spj  = (const float*)d_in[4];
  const float* invs = (const float*)d_in[5];
  const float* GR   = (const float*)d_in[6];
  const float* GIm  = (const float*)d_in[7];
  const float* wm   = (const float*)d_in[8];
  const float* proj = (const float*)d_in[9];
  float* out = (float*)d_out;
  float* ws  = (float*)d_ws;

  k1_xt  <<<1024, 256, 0, stream>>>(x, Wc, bc, ws + OFF_XT);
  k2_xm  <<<4, 512, 0, stream>>>(ws + OFF_XT, ws + OFF_XR, ws + OFF_XI);
  k3_trans<<<NT * 16, 256, 0, stream>>>(GR, GIm, ws + OFF_XR, ws + OFF_XI, ws + OFF_TR);
  k4_beta<<<dim3(4, 4), 64, 0, stream>>>(wm, ws + OFF_XR, ws + OFF_XI, ws + OFF_BE);
  k5_g   <<<dim3(16, 4, 2), 256, 0, stream>>>(spi, spj, invs, ws + OFF_TR, ws + OFF_BE,
                                              ws + OFF_GI, ws + OFF_GJ);
  k6_out <<<dim3(48, 48), 256, 0, stream>>>(proj, ws + OFF_GI, ws + OFF_GJ, out);
}

// Round 2
// 63.458 us; speedup vs baseline: 1.1847x; 1.1847x over previous
//
#include <hip/hip_runtime.h>
#include <math.h>

#define NB 4
#define NCTX 2048
#define NLAT 256
#define NT 34
#define NSUB 16
#define NRK 16
#define NH 768
#define NW 768

// workspace float offsets
#define OFF_XT  0u        // 4*1024 = 4096
#define OFF_TR  4096u     // 4*34*16*16*2 = 69632
#define OFF_BE  73728u    // 4*16*16 = 1024
#define OFF_GI  74752u    // 4*16*768*2 = 98304
#define OFF_GJ  173056u   // 4*16*768*2 = 98304

__device__ __forceinline__ float siglog(float v) {
  return copysignf(log1pf(fabsf(v)), v);
}

// K1: xt[b][j] = sum_i x[b][i]*Wc[j][i] + bc[j]   (one j per block)
__global__ __launch_bounds__(256) void k1_xt(const float* __restrict__ x,
                                             const float* __restrict__ Wc,
                                             const float* __restrict__ bc,
                                             float* __restrict__ xt) {
  const int j = blockIdx.x;
  const int tid = threadIdx.x;
  const float4* w4 = (const float4*)(Wc + (size_t)j * NCTX);
  const float4* x4 = (const float4*)x;
  float a0 = 0.f, a1 = 0.f, a2 = 0.f, a3 = 0.f;
  #pragma unroll
  for (int it = 0; it < 2; ++it) {
    int i = tid + it * 256;
    float4 w = w4[i];
    float4 v0 = x4[i];
    float4 v1 = x4[512 + i];
    float4 v2 = x4[1024 + i];
    float4 v3 = x4[1536 + i];
    a0 += w.x * v0.x + w.y * v0.y + w.z * v0.z + w.w * v0.w;
    a1 += w.x * v1.x + w.y * v1.y + w.z * v1.z + w.w * v1.w;
    a2 += w.x * v2.x + w.y * v2.y + w.z * v2.z + w.w * v2.w;
    a3 += w.x * v3.x + w.y * v3.y + w.z * v3.z + w.w * v3.w;
  }
  __shared__ float red[4][256];
  red[0][tid] = a0; red[1][tid] = a1; red[2][tid] = a2; red[3][tid] = a3;
  __syncthreads();
  const int wv = tid >> 6, lane = tid & 63;
  float s = red[wv][lane] + red[wv][lane + 64] + red[wv][lane + 128] + red[wv][lane + 192];
  #pragma unroll
  for (int off = 32; off > 0; off >>= 1) s += __shfl_down(s, off, 64);
  if (lane == 0) xt[(size_t)wv * 1024 + j] = s + bc[j];
}

// K3: Re/Im einsum over l (4-way l-split across waves), collapsed mag math
// block = (t,c); all 256 threads compute.
__global__ __launch_bounds__(256) void k3_trans(const float* __restrict__ GR,
                                                const float* __restrict__ GIm,
                                                const float* __restrict__ xt,
                                                float* __restrict__ tr) {
  const int t = blockIdx.x >> 4;
  const int c = blockIdx.x & 15;
  const int tid = threadIdx.x;
  __shared__ float gr_s[4096];
  __shared__ float gi_s[4096];
  __shared__ float xr_s[4][256];
  __shared__ float xi_s[4][256];
  __shared__ float2 red[4][64];
  const float4* grp = (const float4*)(GR + (size_t)(t * 16 + c) * 4096);
  const float4* gip = (const float4*)(GIm + (size_t)(t * 16 + c) * 4096);
  float4* grs4 = (float4*)gr_s;
  float4* gis4 = (float4*)gi_s;
  #pragma unroll
  for (int it = 0; it < 4; ++it) {
    int k = tid + it * 256;
    grs4[k] = grp[k];
    gis4[k] = gip[k];
  }
  #pragma unroll
  for (int it = 0; it < 4; ++it) {
    int k = tid + it * 256;
    int b = k >> 8, l = k & 255;
    float a0 = xt[b * 1024 + 2 * l];
    float s0 = xt[b * 1024 + 512 + 2 * l];
    float a1 = xt[b * 1024 + 2 * l + 1];
    float s1 = xt[b * 1024 + 512 + 2 * l + 1];
    xr_s[b][l] = a0 * siglog(s0);
    xi_s[b][l] = a1 * siglog(s1);
  }
  __syncthreads();
  const int r = tid & 15, b = (tid >> 4) & 3, lseg = tid >> 6;
  float are = 0.f, aim = 0.f;
  const int l0 = lseg * 64;
  for (int li = 0; li < 64; ++li) {
    int l = l0 + li;
    float gr = gr_s[l * 16 + r], gi = gi_s[l * 16 + r];
    float vr = xr_s[b][l], vi = xi_s[b][l];
    are += vr * gr - vi * gi;
    aim += vr * gi + vi * gr;
  }
  red[lseg][b * 16 + r] = make_float2(are, aim);
  __syncthreads();
  if (tid < 64) {
    const int rr = tid & 15, bb = tid >> 4;
    float2 s0 = red[0][tid], s1 = red[1][tid], s2 = red[2][tid], s3 = red[3][tid];
    float sre = s0.x + s1.x + s2.x + s3.x;
    float sim = s0.y + s1.y + s2.y + s3.y;
    float mag = sqrtf(sre * sre + sim * sim + 1e-12f);
    float scale = 256.f * mag / (256.f * mag + 1e-12f);
    size_t o = ((((size_t)bb * NT + t) * 16 + c) * 16 + rr) * 2;
    tr[o]     = sre * scale;
    tr[o + 1] = sim * scale;
  }
}

// K4: beta = softmax_r |x @ w_mix|. block = (n, b); thread = (r, lseg of 16 l's)
__global__ __launch_bounds__(256) void k4_beta(const float* __restrict__ wm,
                                               const float* __restrict__ xt,
                                               float* __restrict__ beta) {
  const int n = blockIdx.x, b = blockIdx.y;
  const int tid = threadIdx.x;
  __shared__ float xr_s[256], xi_s[256];
  __shared__ float2 red[16][16];
  {
    int l = tid;
    float a0 = xt[b * 1024 + 2 * l];
    float s0 = xt[b * 1024 + 512 + 2 * l];
    float a1 = xt[b * 1024 + 2 * l + 1];
    float s1 = xt[b * 1024 + 512 + 2 * l + 1];
    xr_s[l] = a0 * siglog(s0);
    xi_s[l] = a1 * siglog(s1);
  }
  __syncthreads();
  const int r = tid & 15, lseg = tid >> 4;
  const float2* wm2 = (const float2*)wm;
  float tre = 0.f, tim = 0.f;
  #pragma unroll
  for (int li = 0; li < 16; ++li) {
    int l = lseg * 16 + li;
    float2 w = wm2[(size_t)l * 256 + n * 16 + r];
    float vr = xr_s[l], vi = xi_s[l];
    tre += vr * w.x - vi * w.y;
    tim += vr * w.y + vi * w.x;
  }
  red[lseg][r] = make_float2(tre, tim);
  __syncthreads();
  if (tid < 16) {
    float sr = 0.f, si = 0.f;
    #pragma unroll
    for (int s = 0; s < 16; ++s) { sr += red[s][tid].x; si += red[s][tid].y; }
    float val = sqrtf(sr * sr + si * si + 1e-12f);
    float m = val;
    #pragma unroll
    for (int off = 8; off > 0; off >>= 1) m = fmaxf(m, __shfl_xor(m, off, 16));
    float e = expf(val - m);
    float ss = e;
    #pragma unroll
    for (int off = 8; off > 0; off >>= 1) ss += __shfl_xor(ss, off, 16);
    beta[(b * 16 + n) * 16 + tid] = e / ss;
  }
}

// K5: build si/sj, apply inv (cmul for I, cdiv for J), beta-weighted r-sum.
__global__ __launch_bounds__(256) void k5_g(const float* __restrict__ space_i,
                                            const float* __restrict__ space_j,
                                            const float* __restrict__ invs,
                                            const float* __restrict__ tr,
                                            const float* __restrict__ beta,
                                            float* __restrict__ gI,
                                            float* __restrict__ gJ) {
  const int c = blockIdx.x, b = blockIdx.y, which = blockIdx.z;
  const int tid = threadIdx.x;
  __shared__ float sh_shift[16][2];
  __shared__ float sh_z[16][16][2];  // [rt][r][comp]
  __shared__ float sh_beta[16];
  if (tid < 32) {
    int r = tid >> 1, comp = tid & 1;
    sh_shift[r][comp] = tr[((((size_t)b * NT + which) * 16 + c) * 16 + r) * 2 + comp];
  }
  if (tid < 16) sh_beta[tid] = beta[(b * 16 + c) * 16 + tid];
  for (int idx = tid; idx < 512; idx += 256) {
    int rt = idx >> 5, r = (idx >> 1) & 15, comp = idx & 1;
    int t = 2 + which * 16 + rt;
    sh_z[rt][r][comp] = tr[((((size_t)b * NT + t) * 16 + c) * 16 + r) * 2 + comp];
  }
  const float inv_re = invs[c * 2], inv_im = invs[c * 2 + 1];
  __syncthreads();
  const float2* sp2 = (const float2*)(which == 0 ? space_i : space_j);
  sp2 += (size_t)c * 16 * 768;
  float2* gout = (float2*)(which == 0 ? gI : gJ);
  gout += (size_t)(b * 16 + c) * 768;
  for (int h = tid; h < 768; h += 256) {
    float pos = ((float)h + 0.5f) * (16.f / 768.f) - 0.5f;
    pos = fminf(fmaxf(pos, 0.f), 15.f);
    int lo = (int)floorf(pos);
    int hi = min(lo + 1, 15);
    float w = pos - (float)lo;
    float accR = 0.f, accI = 0.f;
    #pragma unroll
    for (int r = 0; r < 16; ++r) {
      float2 sp = sp2[r * 768 + h];
      float spr = sp.x + sh_shift[r][0];
      float spi = sp.y + sh_shift[r][1];
      float ztr = sh_z[lo][r][0] * (1.f - w) + sh_z[hi][r][0] * w;
      float zti = sh_z[lo][r][1] * (1.f - w) + sh_z[hi][r][1] * w;
      float sre = spr * ztr - spi * zti;
      float sim = spr * zti + spi * ztr;
      float br = sh_beta[r];
      if (which == 0) {
        accR += br * sre;
        accI += br * sim;
      } else {
        float den = fmaxf(sre * sre + sim * sim, 1e-4f);
        float id = 1.f / den;
        accR += br * (inv_re * sre + inv_im * sim) * id;
        accI += br * (inv_im * sre - inv_re * sim) * id;
      }
    }
    float2 o;
    if (which == 0) {  // gI = cmul(sum, inv)  (cmul linear in first arg)
      o.x = accR * inv_re - accI * inv_im;
      o.y = accR * inv_im + accI * inv_re;
    } else {
      o.x = accR; o.y = accI;
    }
    gout[h] = o;
  }
}

// K6: out[b][h][w] = sum_c (wRe*pc + wIm*ps). 32x32 tile, 2x2 per thread, 4 b.
__global__ __launch_bounds__(256) void k6_out(const float* __restrict__ proj,
                                              const float* __restrict__ gI,
                                              const float* __restrict__ gJ,
                                              float* __restrict__ out) {
  const int w0 = blockIdx.x * 32;
  const int h0 = blockIdx.y * 32;
  const int tid = threadIdx.x;
  const int tw = tid & 15, th = tid >> 4;
  __shared__ float2 gIs[64][32];  // [b*16+c][hh]
  __shared__ float2 gJs[64][32];  // [b*16+c][ww]
  const float2* gI2 = (const float2*)gI;
  const float2* gJ2 = (const float2*)gJ;
  #pragma unroll
  for (int it = 0; it < 8; ++it) {
    int idx = tid + it * 256;
    int i = idx & 31, bcp = idx >> 5;
    gIs[bcp][i] = gI2[(size_t)bcp * 768 + h0 + i];
    gJs[bcp][i] = gJ2[(size_t)bcp * 768 + w0 + i];
  }
  __syncthreads();
  const float4* proj4 = (const float4*)proj;
  float acc[4][4];
  #pragma unroll
  for (int b = 0; b < 4; ++b)
    #pragma unroll
    for (int q = 0; q < 4; ++q) acc[b][q] = 0.f;

  #pragma unroll
  for (int c = 0; c < 16; ++c) {
    float pr[2][2], pi[2][2];
    #pragma unroll
    for (int hh = 0; hh < 2; ++hh) {
      int h = h0 + th * 2 + hh;
      float4 p = proj4[(size_t)(c * 768 + h) * 384 + (w0 >> 1) + tw];
      float rq0 = rsqrtf(p.x * p.x + p.y * p.y + 1e-12f);
      float rq1 = rsqrtf(p.z * p.z + p.w * p.w + 1e-12f);
      pr[hh][0] = p.x * rq0; pi[hh][0] = p.y * rq0;
      pr[hh][1] = p.z * rq1; pi[hh][1] = p.w * rq1;
    }
    #pragma unroll
    for (int b = 0; b < 4; ++b) {
      float2 gi0 = gIs[b * 16 + c][th * 2];
      float2 gi1 = gIs[b * 16 + c][th * 2 + 1];
      float2 gj0 = gJs[b * 16 + c][tw * 2];
      float2 gj1 = gJs[b * 16 + c][tw * 2 + 1];
      {
        float wRe = gi0.x * gj0.x - gi0.y * gj0.y;
        float wIm = gi0.x * gj0.y + gi0.y * gj0.x;
        acc[b][0] += wRe * pr[0][0] + wIm * pi[0][0];
      }
      {
        float wRe = gi0.x * gj1.x - gi0.y * gj1.y;
        float wIm = gi0.x * gj1.y + gi0.y * gj1.x;
        acc[b][1] += wRe * pr[0][1] + wIm * pi[0][1];
      }
      {
        float wRe = gi1.x * gj0.x - gi1.y * gj0.y;
        float wIm = gi1.x * gj0.y + gi1.y * gj0.x;
        acc[b][2] += wRe * pr[1][0] + wIm * pi[1][0];
      }
      {
        float wRe = gi1.x * gj1.x - gi1.y * gj1.y;
        float wIm = gi1.x * gj1.y + gi1.y * gj1.x;
        acc[b][3] += wRe * pr[1][1] + wIm * pi[1][1];
      }
    }
  }
  float2* out2 = (float2*)out;
  #pragma unroll
  for (int b = 0; b < 4; ++b) {
    #pragma unroll
    for (int hh = 0; hh < 2; ++hh) {
      int h = h0 + th * 2 + hh;
      float2 st;
      st.x = acc[b][hh * 2 + 0];
      st.y = acc[b][hh * 2 + 1];
      out2[((size_t)b * 768 + h) * 384 + (w0 >> 1) + tw] = st;
    }
  }
}

extern "C" void kernel_launch(void* const* d_in, const int* in_sizes, int n_in,
                              void* d_out, int out_size, void* d_ws, size_t ws_size,
                              hipStream_t stream) {
  (void)in_sizes; (void)n_in; (void)out_size; (void)ws_size;
  const float* x    = (const float*)d_in[0];
  const float* Wc   = (const float*)d_in[1];
  const float* bc   = (const float*)d_in[2];
  const float* spi  = (const float*)d_in[3];
  const float* spj  = (const float*)d_in[4];
  const float* invs = (const float*)d_in[5];
  const float* GR   = (const float*)d_in[6];
  const float* GIm  = (const float*)d_in[7];
  const float* wm   = (const float*)d_in[8];
  const float* proj = (const float*)d_in[9];
  float* out = (float*)d_out;
  float* ws  = (float*)d_ws;

  k1_xt   <<<1024, 256, 0, stream>>>(x, Wc, bc, ws + OFF_XT);
  k3_trans<<<NT * 16, 256, 0, stream>>>(GR, GIm, ws + OFF_XT, ws + OFF_TR);
  k4_beta <<<dim3(16, 4), 256, 0, stream>>>(wm, ws + OFF_XT, ws + OFF_BE);
  k5_g    <<<dim3(16, 4, 2), 256, 0, stream>>>(spi, spj, invs, ws + OFF_TR, ws + OFF_BE,
                                               ws + OFF_GI, ws + OFF_GJ);
  k6_out  <<<dim3(24, 24), 256, 0, stream>>>(proj, ws + OFF_GI, ws + OFF_GJ, out);
}

// Round 3
// 59.174 us; speedup vs baseline: 1.2704x; 1.0724x over previous
//
#include <hip/hip_runtime.h>
#include <math.h>

#define NCTX 2048
#define NT 34

// workspace float offsets
#define OFF_XR 0u         // 4*256
#define OFF_XI 1024u      // 4*256
#define OFF_TR 2048u      // 4*34*16*16*2 = 69632
#define OFF_GI 71680u     // 4*16*768*2 = 98304
#define OFF_GJ 169984u    // 4*16*768*2 = 98304

__device__ __forceinline__ float siglog(float v) {
  return copysignf(log1pf(fabsf(v)), v);
}

// K1: paired GEMV rows (p, p+512) + siglog mix -> write xr/xi directly.
__global__ __launch_bounds__(256) void k1_xm(const float* __restrict__ x,
                                             const float* __restrict__ Wc,
                                             const float* __restrict__ bc,
                                             float* __restrict__ xr,
                                             float* __restrict__ xi) {
  const int p = blockIdx.x;  // 0..511
  const int tid = threadIdx.x;
  const float4* w1 = (const float4*)(Wc + (size_t)p * NCTX);
  const float4* w2 = (const float4*)(Wc + (size_t)(p + 512) * NCTX);
  const float4* x4 = (const float4*)x;
  float a00 = 0.f, a01 = 0.f, a02 = 0.f, a03 = 0.f;
  float a10 = 0.f, a11 = 0.f, a12 = 0.f, a13 = 0.f;
  #pragma unroll
  for (int it = 0; it < 2; ++it) {
    int i = tid + it * 256;
    float4 wa = w1[i];
    float4 wb = w2[i];
    float4 v0 = x4[i];
    float4 v1 = x4[512 + i];
    float4 v2 = x4[1024 + i];
    float4 v3 = x4[1536 + i];
    a00 += wa.x * v0.x + wa.y * v0.y + wa.z * v0.z + wa.w * v0.w;
    a01 += wa.x * v1.x + wa.y * v1.y + wa.z * v1.z + wa.w * v1.w;
    a02 += wa.x * v2.x + wa.y * v2.y + wa.z * v2.z + wa.w * v2.w;
    a03 += wa.x * v3.x + wa.y * v3.y + wa.z * v3.z + wa.w * v3.w;
    a10 += wb.x * v0.x + wb.y * v0.y + wb.z * v0.z + wb.w * v0.w;
    a11 += wb.x * v1.x + wb.y * v1.y + wb.z * v1.z + wb.w * v1.w;
    a12 += wb.x * v2.x + wb.y * v2.y + wb.z * v2.z + wb.w * v2.w;
    a13 += wb.x * v3.x + wb.y * v3.y + wb.z * v3.z + wb.w * v3.w;
  }
  __shared__ float red[8][256];
  __shared__ float sums[8];
  red[0][tid] = a00; red[1][tid] = a01; red[2][tid] = a02; red[3][tid] = a03;
  red[4][tid] = a10; red[5][tid] = a11; red[6][tid] = a12; red[7][tid] = a13;
  __syncthreads();
  const int wv = tid >> 6, lane = tid & 63;
  #pragma unroll
  for (int q = 0; q < 2; ++q) {
    int combo = wv * 2 + q;  // combo = row*4 + b
    float s = red[combo][lane] + red[combo][lane + 64] +
              red[combo][lane + 128] + red[combo][lane + 192];
    #pragma unroll
    for (int off = 32; off > 0; off >>= 1) s += __shfl_down(s, off, 64);
    if (lane == 0) sums[combo] = s;
  }
  __syncthreads();
  if (tid < 4) {
    float d1 = sums[tid] + bc[p];
    float d2 = sums[4 + tid] + bc[p + 512];
    float v = d1 * siglog(d2);
    float* dst = (p & 1) ? xi : xr;
    dst[tid * 256 + (p >> 1)] = v;
  }
}

// K3: Re/Im einsum over l (4-way l-split), collapsed broadcast-mag math.
__global__ __launch_bounds__(256) void k3_trans(const float* __restrict__ GR,
                                                const float* __restrict__ GIm,
                                                const float* __restrict__ xr,
                                                const float* __restrict__ xi,
                                                float* __restrict__ tr) {
  const int t = blockIdx.x >> 4;
  const int c = blockIdx.x & 15;
  const int tid = threadIdx.x;
  __shared__ float gr_s[4096];
  __shared__ float gi_s[4096];
  __shared__ float xr_s[1024];  // [b*256+l]
  __shared__ float xi_s[1024];
  __shared__ float2 red2[4][64];
  const float4* grp = (const float4*)(GR + (size_t)(t * 16 + c) * 4096);
  const float4* gip = (const float4*)(GIm + (size_t)(t * 16 + c) * 4096);
  #pragma unroll
  for (int it = 0; it < 4; ++it) {
    int k = tid + it * 256;
    ((float4*)gr_s)[k] = grp[k];
    ((float4*)gi_s)[k] = gip[k];
  }
  ((float4*)xr_s)[tid] = ((const float4*)xr)[tid];
  ((float4*)xi_s)[tid] = ((const float4*)xi)[tid];
  __syncthreads();
  const int r = tid & 15, b = (tid >> 4) & 3, lseg = tid >> 6;
  float are = 0.f, aim = 0.f;
  const int l0 = lseg * 64;
  for (int li = 0; li < 64; ++li) {
    int l = l0 + li;
    float gr = gr_s[l * 16 + r], gi = gi_s[l * 16 + r];
    float vr = xr_s[b * 256 + l], vi = xi_s[b * 256 + l];
    are += vr * gr - vi * gi;
    aim += vr * gi + vi * gr;
  }
  red2[lseg][b * 16 + r] = make_float2(are, aim);
  __syncthreads();
  if (tid < 64) {
    const int rr = tid & 15, bb = tid >> 4;
    float2 s0 = red2[0][tid], s1 = red2[1][tid], s2 = red2[2][tid], s3 = red2[3][tid];
    float sre = s0.x + s1.x + s2.x + s3.x;
    float sim = s0.y + s1.y + s2.y + s3.y;
    float mag = sqrtf(sre * sre + sim * sim + 1e-12f);
    float scale = 256.f * mag / (256.f * mag + 1e-12f);
    size_t o = ((((size_t)bb * NT + t) * 16 + c) * 16 + rr) * 2;
    tr[o]     = sre * scale;
    tr[o + 1] = sim * scale;
  }
}

// K5: beta softmax (folded from old k4) + build si/sj, apply inv, beta-weighted r-sum.
__global__ __launch_bounds__(256) void k5_g(const float* __restrict__ space_i,
                                            const float* __restrict__ space_j,
                                            const float* __restrict__ invs,
                                            const float* __restrict__ tr,
                                            const float* __restrict__ xr,
                                            const float* __restrict__ xi,
                                            const float* __restrict__ wm,
                                            float* __restrict__ gI,
                                            float* __restrict__ gJ) {
  const int c = blockIdx.x, b = blockIdx.y, which = blockIdx.z;
  const int tid = threadIdx.x;
  __shared__ float xr_s[256], xi_s[256];
  __shared__ float2 redb[16][16];
  __shared__ float sh_beta[16];
  __shared__ float sh_shift[16][2];
  __shared__ float sh_z[16][16][2];  // [rt][r][comp]
  xr_s[tid] = xr[b * 256 + tid];
  xi_s[tid] = xi[b * 256 + tid];
  if (tid < 32) {
    int r = tid >> 1, comp = tid & 1;
    sh_shift[r][comp] = tr[((((size_t)b * NT + which) * 16 + c) * 16 + r) * 2 + comp];
  }
  for (int idx = tid; idx < 512; idx += 256) {
    int rt = idx >> 5, r = (idx >> 1) & 15, comp = idx & 1;
    int t = 2 + which * 16 + rt;
    sh_z[rt][r][comp] = tr[((((size_t)b * NT + t) * 16 + c) * 16 + r) * 2 + comp];
  }
  __syncthreads();
  // beta: tmix = x @ w_mix (only columns c*16..c*16+15), softmax over r
  {
    const int r = tid & 15, lseg = tid >> 4;
    const float2* wm2 = (const float2*)wm;
    float tre = 0.f, tim = 0.f;
    #pragma unroll
    for (int li = 0; li < 16; ++li) {
      int l = lseg * 16 + li;
      float2 w = wm2[(size_t)l * 256 + c * 16 + r];
      float vr = xr_s[l], vi = xi_s[l];
      tre += vr * w.x - vi * w.y;
      tim += vr * w.y + vi * w.x;
    }
    redb[lseg][r] = make_float2(tre, tim);
  }
  __syncthreads();
  if (tid < 16) {
    float sr = 0.f, si = 0.f;
    #pragma unroll
    for (int s = 0; s < 16; ++s) { sr += redb[s][tid].x; si += redb[s][tid].y; }
    float val = sqrtf(sr * sr + si * si + 1e-12f);
    float m = val;
    #pragma unroll
    for (int off = 8; off > 0; off >>= 1) m = fmaxf(m, __shfl_xor(m, off, 16));
    float e = expf(val - m);
    float ss = e;
    #pragma unroll
    for (int off = 8; off > 0; off >>= 1) ss += __shfl_xor(ss, off, 16);
    sh_beta[tid] = e / ss;
  }
  const float inv_re = invs[c * 2], inv_im = invs[c * 2 + 1];
  __syncthreads();
  const float2* sp2 = (const float2*)(which == 0 ? space_i : space_j);
  sp2 += (size_t)c * 16 * 768;
  float2* gout = (float2*)(which == 0 ? gI : gJ);
  gout += (size_t)(b * 16 + c) * 768;
  for (int h = tid; h < 768; h += 256) {
    float pos = ((float)h + 0.5f) * (16.f / 768.f) - 0.5f;
    pos = fminf(fmaxf(pos, 0.f), 15.f);
    int lo = (int)floorf(pos);
    int hi = min(lo + 1, 15);
    float w = pos - (float)lo;
    float accR = 0.f, accI = 0.f;
    #pragma unroll
    for (int r = 0; r < 16; ++r) {
      float2 sp = sp2[r * 768 + h];
      float spr = sp.x + sh_shift[r][0];
      float spi = sp.y + sh_shift[r][1];
      float ztr = sh_z[lo][r][0] * (1.f - w) + sh_z[hi][r][0] * w;
      float zti = sh_z[lo][r][1] * (1.f - w) + sh_z[hi][r][1] * w;
      float sre = spr * ztr - spi * zti;
      float sim = spr * zti + spi * ztr;
      float br = sh_beta[r];
      if (which == 0) {
        accR += br * sre;
        accI += br * sim;
      } else {
        float den = fmaxf(sre * sre + sim * sim, 1e-4f);
        float id = 1.f / den;
        accR += br * (inv_re * sre + inv_im * sim) * id;
        accI += br * (inv_im * sre - inv_re * sim) * id;
      }
    }
    float2 o;
    if (which == 0) {  // gI = cmul(sum, inv)  (cmul linear in first arg)
      o.x = accR * inv_re - accI * inv_im;
      o.y = accR * inv_im + accI * inv_re;
    } else {
      o.x = accR; o.y = accI;
    }
    gout[h] = o;
  }
}

// K6: out[b][h][w] = sum_c (wRe*pc + wIm*ps). 32x32 tile, 2x2 per thread, 4 b.
__global__ __launch_bounds__(256) void k6_out(const float* __restrict__ proj,
                                              const float* __restrict__ gI,
                                              const float* __restrict__ gJ,
                                              float* __restrict__ out) {
  const int w0 = blockIdx.x * 32;
  const int h0 = blockIdx.y * 32;
  const int tid = threadIdx.x;
  const int tw = tid & 15, th = tid >> 4;
  __shared__ float2 gIs[64][32];  // [b*16+c][hh]
  __shared__ float2 gJs[64][32];  // [b*16+c][ww]
  const float2* gI2 = (const float2*)gI;
  const float2* gJ2 = (const float2*)gJ;
  #pragma unroll
  for (int it = 0; it < 8; ++it) {
    int idx = tid + it * 256;
    int i = idx & 31, bcp = idx >> 5;
    gIs[bcp][i] = gI2[(size_t)bcp * 768 + h0 + i];
    gJs[bcp][i] = gJ2[(size_t)bcp * 768 + w0 + i];
  }
  __syncthreads();
  const float4* proj4 = (const float4*)proj;
  float acc[4][4];
  #pragma unroll
  for (int b = 0; b < 4; ++b)
    #pragma unroll
    for (int q = 0; q < 4; ++q) acc[b][q] = 0.f;

  #pragma unroll
  for (int c = 0; c < 16; ++c) {
    float pr[2][2], pi[2][2];
    #pragma unroll
    for (int hh = 0; hh < 2; ++hh) {
      int h = h0 + th * 2 + hh;
      float4 p = proj4[(size_t)(c * 768 + h) * 384 + (w0 >> 1) + tw];
      float rq0 = rsqrtf(p.x * p.x + p.y * p.y + 1e-12f);
      float rq1 = rsqrtf(p.z * p.z + p.w * p.w + 1e-12f);
      pr[hh][0] = p.x * rq0; pi[hh][0] = p.y * rq0;
      pr[hh][1] = p.z * rq1; pi[hh][1] = p.w * rq1;
    }
    #pragma unroll
    for (int b = 0; b < 4; ++b) {
      float2 gi0 = gIs[b * 16 + c][th * 2];
      float2 gi1 = gIs[b * 16 + c][th * 2 + 1];
      float2 gj0 = gJs[b * 16 + c][tw * 2];
      float2 gj1 = gJs[b * 16 + c][tw * 2 + 1];
      {
        float wRe = gi0.x * gj0.x - gi0.y * gj0.y;
        float wIm = gi0.x * gj0.y + gi0.y * gj0.x;
        acc[b][0] += wRe * pr[0][0] + wIm * pi[0][0];
      }
      {
        float wRe = gi0.x * gj1.x - gi0.y * gj1.y;
        float wIm = gi0.x * gj1.y + gi0.y * gj1.x;
        acc[b][1] += wRe * pr[0][1] + wIm * pi[0][1];
      }
      {
        float wRe = gi1.x * gj0.x - gi1.y * gj0.y;
        float wIm = gi1.x * gj0.y + gi1.y * gj0.x;
        acc[b][2] += wRe * pr[1][0] + wIm * pi[1][0];
      }
      {
        float wRe = gi1.x * gj1.x - gi1.y * gj1.y;
        float wIm = gi1.x * gj1.y + gi1.y * gj1.x;
        acc[b][3] += wRe * pr[1][1] + wIm * pi[1][1];
      }
    }
  }
  float2* out2 = (float2*)out;
  #pragma unroll
  for (int b = 0; b < 4; ++b) {
    #pragma unroll
    for (int hh = 0; hh < 2; ++hh) {
      int h = h0 + th * 2 + hh;
      float2 st;
      st.x = acc[b][hh * 2 + 0];
      st.y = acc[b][hh * 2 + 1];
      out2[((size_t)b * 768 + h) * 384 + (w0 >> 1) + tw] = st;
    }
  }
}

extern "C" void kernel_launch(void* const* d_in, const int* in_sizes, int n_in,
                              void* d_out, int out_size, void* d_ws, size_t ws_size,
                              hipStream_t stream) {
  (void)in_sizes; (void)n_in; (void)out_size; (void)ws_size;
  const float* x    = (const float*)d_in[0];
  const float* Wc   = (const float*)d_in[1];
  const float* bc   = (const float*)d_in[2];
  const float* spi  = (const float*)d_in[3];
  const float* spj  = (const float*)d_in[4];
  const float* invs = (const float*)d_in[5];
  const float* GR   = (const float*)d_in[6];
  const float* GIm  = (const float*)d_in[7];
  const float* wm   = (const float*)d_in[8];
  const float* proj = (const float*)d_in[9];
  float* out = (float*)d_out;
  float* ws  = (float*)d_ws;

  k1_xm   <<<512, 256, 0, stream>>>(x, Wc, bc, ws + OFF_XR, ws + OFF_XI);
  k3_trans<<<NT * 16, 256, 0, stream>>>(GR, GIm, ws + OFF_XR, ws + OFF_XI, ws + OFF_TR);
  k5_g    <<<dim3(16, 4, 2), 256, 0, stream>>>(spi, spj, invs, ws + OFF_TR,
                                               ws + OFF_XR, ws + OFF_XI, wm,
                                               ws + OFF_GI, ws + OFF_GJ);
  k6_out  <<<dim3(24, 24), 256, 0, stream>>>(proj, ws + OFF_GI, ws + OFF_GJ, out);
}

// Round 5
// 42.904 us; speedup vs baseline: 1.7522x; 1.3792x over previous
//
#include <hip/hip_runtime.h>
#include <math.h>

#define NCTX 2048
#define NT 34

typedef float f4 __attribute__((ext_vector_type(4)));
typedef float f2 __attribute__((ext_vector_type(2)));

// workspace float offsets
#define OFF_XR 0u         // 4*256
#define OFF_XI 1024u      // 4*256
#define OFF_TR 2048u      // 4*34*16*16*2 = 69632
#define OFF_GI 71680u     // 4*16*768*2 = 98304
#define OFF_GJ 169984u    // 4*16*768*2 = 98304

__device__ __forceinline__ float siglog(float v) {
  return copysignf(log1pf(fabsf(v)), v);
}

__device__ __forceinline__ f4 ntload4(const float* p) {
  return __builtin_nontemporal_load((const f4*)p);
}

// K1: paired GEMV rows (p, p+512) + siglog mix -> write xr/xi directly.
__global__ __launch_bounds__(256) void k1_xm(const float* __restrict__ x,
                                             const float* __restrict__ Wc,
                                             const float* __restrict__ bc,
                                             float* __restrict__ xr,
                                             float* __restrict__ xi) {
  const int p = blockIdx.x;  // 0..511
  const int tid = threadIdx.x;
  const float* w1 = Wc + (size_t)p * NCTX;
  const float* w2 = Wc + (size_t)(p + 512) * NCTX;
  const f4* x4 = (const f4*)x;
  float a00 = 0.f, a01 = 0.f, a02 = 0.f, a03 = 0.f;
  float a10 = 0.f, a11 = 0.f, a12 = 0.f, a13 = 0.f;
  #pragma unroll
  for (int it = 0; it < 2; ++it) {
    int i = tid + it * 256;
    f4 wa = ntload4(w1 + i * 4);
    f4 wb = ntload4(w2 + i * 4);
    f4 v0 = x4[i];
    f4 v1 = x4[512 + i];
    f4 v2 = x4[1024 + i];
    f4 v3 = x4[1536 + i];
    a00 += wa.x * v0.x + wa.y * v0.y + wa.z * v0.z + wa.w * v0.w;
    a01 += wa.x * v1.x + wa.y * v1.y + wa.z * v1.z + wa.w * v1.w;
    a02 += wa.x * v2.x + wa.y * v2.y + wa.z * v2.z + wa.w * v2.w;
    a03 += wa.x * v3.x + wa.y * v3.y + wa.z * v3.z + wa.w * v3.w;
    a10 += wb.x * v0.x + wb.y * v0.y + wb.z * v0.z + wb.w * v0.w;
    a11 += wb.x * v1.x + wb.y * v1.y + wb.z * v1.z + wb.w * v1.w;
    a12 += wb.x * v2.x + wb.y * v2.y + wb.z * v2.z + wb.w * v2.w;
    a13 += wb.x * v3.x + wb.y * v3.y + wb.z * v3.z + wb.w * v3.w;
  }
  __shared__ float red[8][256];
  __shared__ float sums[8];
  red[0][tid] = a00; red[1][tid] = a01; red[2][tid] = a02; red[3][tid] = a03;
  red[4][tid] = a10; red[5][tid] = a11; red[6][tid] = a12; red[7][tid] = a13;
  __syncthreads();
  const int wv = tid >> 6, lane = tid & 63;
  #pragma unroll
  for (int q = 0; q < 2; ++q) {
    int combo = wv * 2 + q;
    float s = red[combo][lane] + red[combo][lane + 64] +
              red[combo][lane + 128] + red[combo][lane + 192];
    #pragma unroll
    for (int off = 32; off > 0; off >>= 1) s += __shfl_down(s, off, 64);
    if (lane == 0) sums[combo] = s;
  }
  __syncthreads();
  if (tid < 4) {
    float d1 = sums[tid] + bc[p];
    float d2 = sums[4 + tid] + bc[p + 512];
    float v = d1 * siglog(d2);
    float* dst = (p & 1) ? xi : xr;
    dst[tid * 256 + (p >> 1)] = v;
  }
}

// K3: einsum over l with G transposed into LDS [r][l] so the inner loop is
// all ds_read_b128 (was 256 scalar ds_read_b32 per thread).
__global__ __launch_bounds__(256) void k3_trans(const float* __restrict__ GR,
                                                const float* __restrict__ GIm,
                                                const float* __restrict__ xr,
                                                const float* __restrict__ xi,
                                                float* __restrict__ tr) {
  const int t = blockIdx.x >> 4;
  const int c = blockIdx.x & 15;
  const int tid = threadIdx.x;
  __shared__ float grT[16][260];  // [r][l], pad 260
  __shared__ float giT[16][260];
  __shared__ float xr_s[1024];    // [b*256+l]
  __shared__ float xi_s[1024];
  __shared__ float2 red2[4][64];
  const float* grp = GR + (size_t)(t * 16 + c) * 4096;
  const float* gip = GIm + (size_t)(t * 16 + c) * 4096;
  #pragma unroll
  for (int it = 0; it < 4; ++it) {
    int k = tid + it * 256;          // float4 index over [l][r]
    int l = k >> 2, q = (k & 3) * 4; // r-start
    f4 g = ntload4(grp + k * 4);
    grT[q + 0][l] = g.x; grT[q + 1][l] = g.y; grT[q + 2][l] = g.z; grT[q + 3][l] = g.w;
    f4 h = ntload4(gip + k * 4);
    giT[q + 0][l] = h.x; giT[q + 1][l] = h.y; giT[q + 2][l] = h.z; giT[q + 3][l] = h.w;
  }
  ((f4*)xr_s)[tid] = ((const f4*)xr)[tid];
  ((f4*)xi_s)[tid] = ((const f4*)xi)[tid];
  __syncthreads();
  const int r = tid & 15, b = (tid >> 4) & 3, lseg = tid >> 6;
  const f4* grv = (const f4*)&grT[r][lseg * 64];
  const f4* giv = (const f4*)&giT[r][lseg * 64];
  const f4* xrv = (const f4*)&xr_s[b * 256 + lseg * 64];
  const f4* xiv = (const f4*)&xi_s[b * 256 + lseg * 64];
  float are = 0.f, aim = 0.f;
  #pragma unroll
  for (int li = 0; li < 16; ++li) {
    f4 g = grv[li], gg = giv[li], vr = xrv[li], vi = xiv[li];
    are += vr.x * g.x - vi.x * gg.x;  aim += vr.x * gg.x + vi.x * g.x;
    are += vr.y * g.y - vi.y * gg.y;  aim += vr.y * gg.y + vi.y * g.y;
    are += vr.z * g.z - vi.z * gg.z;  aim += vr.z * gg.z + vi.z * g.z;
    are += vr.w * g.w - vi.w * gg.w;  aim += vr.w * gg.w + vi.w * g.w;
  }
  red2[lseg][b * 16 + r] = make_float2(are, aim);
  __syncthreads();
  if (tid < 64) {
    const int rr = tid & 15, bb = tid >> 4;
    float2 s0 = red2[0][tid], s1 = red2[1][tid], s2 = red2[2][tid], s3 = red2[3][tid];
    float sre = s0.x + s1.x + s2.x + s3.x;
    float sim = s0.y + s1.y + s2.y + s3.y;
    float mag = sqrtf(sre * sre + sim * sim + 1e-12f);
    float scale = 256.f * mag / (256.f * mag + 1e-12f);
    size_t o = ((((size_t)bb * NT + t) * 16 + c) * 16 + rr) * 2;
    tr[o]     = sre * scale;
    tr[o + 1] = sim * scale;
  }
}

// K5: beta softmax + build si/sj, apply inv, beta-weighted r-sum.
// grid (c=16, b=4, z=6): which = z/3, h-segment = z%3; one h per thread.
__global__ __launch_bounds__(256) void k5_g(const float* __restrict__ space_i,
                                            const float* __restrict__ space_j,
                                            const float* __restrict__ invs,
                                            const float* __restrict__ tr,
                                            const float* __restrict__ xr,
                                            const float* __restrict__ xi,
                                            const float* __restrict__ wm,
                                            float* __restrict__ gI,
                                            float* __restrict__ gJ) {
  const int c = blockIdx.x, b = blockIdx.y;
  const int which = blockIdx.z / 3, seg = blockIdx.z % 3;
  const int tid = threadIdx.x;
  __shared__ float xr_s[256], xi_s[256];
  __shared__ float2 redb[16][16];
  __shared__ float sh_beta[16];
  __shared__ float sh_shift[16][2];
  __shared__ float sh_z[16][16][2];  // [rt][r][comp]
  xr_s[tid] = xr[b * 256 + tid];
  xi_s[tid] = xi[b * 256 + tid];
  if (tid < 32) {
    int r = tid >> 1, comp = tid & 1;
    sh_shift[r][comp] = tr[((((size_t)b * NT + which) * 16 + c) * 16 + r) * 2 + comp];
  }
  for (int idx = tid; idx < 512; idx += 256) {
    int rt = idx >> 5, r = (idx >> 1) & 15, comp = idx & 1;
    int t = 2 + which * 16 + rt;
    sh_z[rt][r][comp] = tr[((((size_t)b * NT + t) * 16 + c) * 16 + r) * 2 + comp];
  }
  __syncthreads();
  {
    const int r = tid & 15, lseg = tid >> 4;
    const float2* wm2 = (const float2*)wm;
    float tre = 0.f, tim = 0.f;
    #pragma unroll
    for (int li = 0; li < 16; ++li) {
      int l = lseg * 16 + li;
      float2 w = wm2[(size_t)l * 256 + c * 16 + r];
      float vr = xr_s[l], vi = xi_s[l];
      tre += vr * w.x - vi * w.y;
      tim += vr * w.y + vi * w.x;
    }
    redb[lseg][r] = make_float2(tre, tim);
  }
  __syncthreads();
  if (tid < 16) {
    float sr = 0.f, si = 0.f;
    #pragma unroll
    for (int s = 0; s < 16; ++s) { sr += redb[s][tid].x; si += redb[s][tid].y; }
    float val = sqrtf(sr * sr + si * si + 1e-12f);
    float m = val;
    #pragma unroll
    for (int off = 8; off > 0; off >>= 1) m = fmaxf(m, __shfl_xor(m, off, 16));
    float e = expf(val - m);
    float ss = e;
    #pragma unroll
    for (int off = 8; off > 0; off >>= 1) ss += __shfl_xor(ss, off, 16);
    sh_beta[tid] = e / ss;
  }
  const float inv_re = invs[c * 2], inv_im = invs[c * 2 + 1];
  __syncthreads();
  const float2* sp2 = (const float2*)(which == 0 ? space_i : space_j);
  sp2 += (size_t)c * 16 * 768;
  float2* gout = (float2*)(which == 0 ? gI : gJ);
  gout += (size_t)(b * 16 + c) * 768;
  const int h = seg * 256 + tid;
  float pos = ((float)h + 0.5f) * (16.f / 768.f) - 0.5f;
  pos = fminf(fmaxf(pos, 0.f), 15.f);
  int lo = (int)floorf(pos);
  int hi = min(lo + 1, 15);
  float w = pos - (float)lo;
  float accR = 0.f, accI = 0.f;
  #pragma unroll
  for (int r = 0; r < 16; ++r) {
    float2 sp = sp2[r * 768 + h];
    float spr = sp.x + sh_shift[r][0];
    float spi = sp.y + sh_shift[r][1];
    float ztr = sh_z[lo][r][0] * (1.f - w) + sh_z[hi][r][0] * w;
    float zti = sh_z[lo][r][1] * (1.f - w) + sh_z[hi][r][1] * w;
    float sre = spr * ztr - spi * zti;
    float sim = spr * zti + spi * ztr;
    float br = sh_beta[r];
    if (which == 0) {
      accR += br * sre;
      accI += br * sim;
    } else {
      float den = fmaxf(sre * sre + sim * sim, 1e-4f);
      float id = 1.f / den;
      accR += br * (inv_re * sre + inv_im * sim) * id;
      accI += br * (inv_im * sre - inv_re * sim) * id;
    }
  }
  float2 o;
  if (which == 0) {  // gI = cmul(sum, inv)  (cmul linear in first arg)
    o.x = accR * inv_re - accI * inv_im;
    o.y = accR * inv_im + accI * inv_re;
  } else {
    o.x = accR; o.y = accI;
  }
  gout[h] = o;
}

// K6: out[b][h][w] = sum_c (wRe*pc + wIm*ps). 32x32 tile, 2x2 per thread, 4 b.
// c-loop at unroll 1 with explicit depth-1 prefetch: bounded VGPR, no spill.
__global__ __launch_bounds__(256) void k6_out(const float* __restrict__ proj,
                                              const float* __restrict__ gI,
                                              const float* __restrict__ gJ,
                                              float* __restrict__ out) {
  const int w0 = blockIdx.x * 32;
  const int h0 = blockIdx.y * 32;
  const int tid = threadIdx.x;
  const int tw = tid & 15, th = tid >> 4;
  __shared__ float2 gIs[64][32];  // [b*16+c][hh]
  __shared__ float2 gJs[64][32];  // [b*16+c][ww]
  const float2* gI2 = (const float2*)gI;
  const float2* gJ2 = (const float2*)gJ;
  #pragma unroll
  for (int it = 0; it < 8; ++it) {
    int idx = tid + it * 256;
    int i = idx & 31, bcp = idx >> 5;
    gIs[bcp][i] = gI2[(size_t)bcp * 768 + h0 + i];
    gJs[bcp][i] = gJ2[(size_t)bcp * 768 + w0 + i];
  }
  __syncthreads();
  const float* pp = proj + ((size_t)(h0 + th * 2) * 384 + (w0 >> 1) + tw) * 4;
  float acc[4][4];
  #pragma unroll
  for (int b = 0; b < 4; ++b)
    #pragma unroll
    for (int q = 0; q < 4; ++q) acc[b][q] = 0.f;

  f4 pa = ntload4(pp);
  f4 pb = ntload4(pp + 384 * 4);
  #pragma unroll 1
  for (int c = 0; c < 16; ++c) {
    f4 c0 = pa, c1 = pb;
    if (c < 15) {
      size_t nxt = (size_t)(c + 1) * 768 * 384 * 4;
      pa = ntload4(pp + nxt);
      pb = ntload4(pp + nxt + 384 * 4);
    }
    float rq00 = rsqrtf(c0.x * c0.x + c0.y * c0.y + 1e-12f);
    float rq01 = rsqrtf(c0.z * c0.z + c0.w * c0.w + 1e-12f);
    float rq10 = rsqrtf(c1.x * c1.x + c1.y * c1.y + 1e-12f);
    float rq11 = rsqrtf(c1.z * c1.z + c1.w * c1.w + 1e-12f);
    float pr00 = c0.x * rq00, pi00 = c0.y * rq00;  // hh0,ww0
    float pr01 = c0.z * rq01, pi01 = c0.w * rq01;  // hh0,ww1
    float pr10 = c1.x * rq10, pi10 = c1.y * rq10;  // hh1,ww0
    float pr11 = c1.z * rq11, pi11 = c1.w * rq11;  // hh1,ww1
    #pragma unroll
    for (int b = 0; b < 4; ++b) {
      float2 gi0 = gIs[b * 16 + c][th * 2];
      float2 gi1 = gIs[b * 16 + c][th * 2 + 1];
      float2 gj0 = gJs[b * 16 + c][tw * 2];
      float2 gj1 = gJs[b * 16 + c][tw * 2 + 1];
      acc[b][0] += (gi0.x * gj0.x - gi0.y * gj0.y) * pr00 + (gi0.x * gj0.y + gi0.y * gj0.x) * pi00;
      acc[b][1] += (gi0.x * gj1.x - gi0.y * gj1.y) * pr01 + (gi0.x * gj1.y + gi0.y * gj1.x) * pi01;
      acc[b][2] += (gi1.x * gj0.x - gi1.y * gj0.y) * pr10 + (gi1.x * gj0.y + gi1.y * gj0.x) * pi10;
      acc[b][3] += (gi1.x * gj1.x - gi1.y * gj1.y) * pr11 + (gi1.x * gj1.y + gi1.y * gj1.x) * pi11;
    }
  }
  #pragma unroll
  for (int b = 0; b < 4; ++b) {
    #pragma unroll
    for (int hh = 0; hh < 2; ++hh) {
      int h = h0 + th * 2 + hh;
      f2 st;
      st.x = acc[b][hh * 2 + 0];
      st.y = acc[b][hh * 2 + 1];
      __builtin_nontemporal_store(st,
          (f2*)(out + (((size_t)b * 768 + h) * 384 + (w0 >> 1) + tw) * 2));
    }
  }
}

extern "C" void kernel_launch(void* const* d_in, const int* in_sizes, int n_in,
                              void* d_out, int out_size, void* d_ws, size_t ws_size,
                              hipStream_t stream) {
  (void)in_sizes; (void)n_in; (void)out_size; (void)ws_size;
  const float* x    = (const float*)d_in[0];
  const float* Wc   = (const float*)d_in[1];
  const float* bc   = (const float*)d_in[2];
  const float* spi  = (const float*)d_in[3];
  const float* spj  = (const float*)d_in[4];
  const float* invs = (const float*)d_in[5];
  const float* GR   = (const float*)d_in[6];
  const float* GIm  = (const float*)d_in[7];
  const float* wm   = (const float*)d_in[8];
  const float* proj = (const float*)d_in[9];
  float* out = (float*)d_out;
  float* ws  = (float*)d_ws;

  k1_xm   <<<512, 256, 0, stream>>>(x, Wc, bc, ws + OFF_XR, ws + OFF_XI);
  k3_trans<<<NT * 16, 256, 0, stream>>>(GR, GIm, ws + OFF_XR, ws + OFF_XI, ws + OFF_TR);
  k5_g    <<<dim3(16, 4, 6), 256, 0, stream>>>(spi, spj, invs, ws + OFF_TR,
                                               ws + OFF_XR, ws + OFF_XI, wm,
                                               ws + OFF_GI, ws + OFF_GJ);
  k6_out  <<<dim3(24, 24), 256, 0, stream>>>(proj, ws + OFF_GI, ws + OFF_GJ, out);
}